// Round 4
// baseline (726.832 us; speedup 1.0000x reference)
//
#include <hip/hip_runtime.h>
#include <hip/hip_bf16.h>

// ---------------------------------------------------------------------------
// D-MPNN molecule encoder, round 6: W-in-REGISTERS GEMM, double-buffered A.
//
// Round-5 diagnosis: 128KB W-in-LDS forced 1 block/CU and a serialized
// single-At chain (period 8.3K cy vs ~2K compute). Each wave only reads 32
// cols x KP of W = 16 short8 = 64 VGPRs -> hold W in registers instead.
// LDS = 2 x 16KB At double buffer, 1 barrier/tile, 2 blocks/CU, addC read
// directly from global in the epilogue (no LDS roundtrip, no extra barriers).
//
//   step1 : buf0 = f_bonds @ W_i                    (pre-relu bf16)  [B,256]
//   iter1 : amsg=gsum(buf0); buf1=relu(buf0 + (amsg[b2a]-relu(buf0[rev]))@W_h)
//   iter2 : amsg=gsum(buf1); buf0=relu(buf0 + (amsg[b2a]-relu(buf1[rev]))@W_h)
//   final : amsg=gsum(buf0)
//   step4a: fbuf(f32) = f_atoms @ W_o[0:133]        (partials, in buf1 mem)
//   step4b: amsg = relu(fbuf + amsg @ W_o[133:] + b)   (in-place)
//   mean  : molv -> A1' planes;  MLP: bf16 hi/lo-split MFMA GEMMs (K3=1536)
// ---------------------------------------------------------------------------

typedef __hip_bfloat16 bf16;
typedef __attribute__((ext_vector_type(8))) short short8;
typedef __attribute__((ext_vector_type(4))) short short4v;
typedef __attribute__((ext_vector_type(4))) float f32x4;
typedef __attribute__((ext_vector_type(4), aligned(4))) float f32x4u;

__device__ __forceinline__ float b2f(bf16 x) { return __bfloat162float(x); }
__device__ __forceinline__ bf16  f2b(float x) { return __float2bfloat16(x); }
__device__ __forceinline__ float bs2f(short s) {
    unsigned int u = ((unsigned int)(unsigned short)s) << 16;
    float f; __builtin_memcpy(&f, &u, 4); return f;
}
__device__ __forceinline__ short f2bs(float f) {
    bf16 b = __float2bfloat16(f);
    short s; __builtin_memcpy(&s, &b, 2); return s;
}

#define GRID 512   // 2 blocks per CU
#define TR 32      // tile rows; 200000%32==0, 100000%32==0

// ---------------------------------------------------------------------------
// W-in-registers GEMM. N fixed 256. KP in {192,256}.
// Each of 8 waves owns 32 output cols; its W slice = 2 x NK short8 in VGPRs.
// MODE: 0 = f32 rows; 1 = diff amsg[g1]-relu(msg[g2]); 2 = plain bf16 rows
// ADDC: 0 none, 1 bf16 global read in epilogue, 2 f32 global read in epilogue
// ---------------------------------------------------------------------------
template <int KP, int MODE, bool RELU, int ADDC, bool HASBIAS, bool OUTF32>
__global__ __launch_bounds__(512, 4) void gemm_wres(
    int M, int ntiles, int Ktrue,
    const float* __restrict__ Af,
    const bf16* __restrict__ Ab1, const bf16* __restrict__ Ab2,
    const int* __restrict__ g1, const int* __restrict__ g2,
    const bf16* __restrict__ Wt,       // [256][KP] bf16 zero-padded
    const float* __restrict__ bias,    // [256] or null
    const bf16* __restrict__ addB, const float* __restrict__ addF,
    bf16* __restrict__ outB, float* __restrict__ outF)
{
    constexpr int NK  = KP / 32;       // K-steps (8 or 6)
    constexpr int KP2 = KP * 2;        // LDS row stride bytes
    __shared__ bf16 At[2][TR * KP];    // 2 x 16KB (KP=256) / 2 x 12KB (KP=192)

    const int t = threadIdx.x;
    int tile = blockIdx.x;
    if (tile >= ntiles) return;        // block-uniform

    const int wave = t >> 6, lane = t & 63;
    const int mrow = lane & 15, kq = lane >> 4;
    const int r = t >> 4, j = t & 15;  // staging: 16 threads per row

    // ---- W slice into registers: rows wave*32+tn*16+mrow, k-slice kq*8 ----
    short8 wreg[2][NK];
    #pragma unroll
    for (int tn = 0; tn < 2; tn++) {
        const bf16* wp = Wt + (size_t)(wave * 32 + tn * 16 + mrow) * KP + kq * 8;
        #pragma unroll
        for (int ks = 0; ks < NK; ks++)
            wreg[tn][ks] = *(const short8*)(wp + ks * 32);
    }
    float biasReg[2] = {0.f, 0.f};
    if (HASBIAS) {
        #pragma unroll
        for (int tn = 0; tn < 2; tn++)
            biasReg[tn] = bias[wave * 32 + tn * 16 + mrow];
    }

    // staging registers (one tile in flight)
    short8 pA[2], pB[2];
    f32x4  pF[3];

    auto prefA = [&](int tl) {
        int row = tl * TR + r;
        if (MODE == 1) {
            int r1 = g1[row], r2 = g2[row];
            const char* s1 = (const char*)(Ab1 + ((size_t)r1 << 8));
            const char* s2 = (const char*)(Ab2 + ((size_t)r2 << 8));
            #pragma unroll
            for (int u = 0; u < 2; u++) {
                pA[u] = *(const short8*)(s1 + ((j + 16 * u) << 4));
                pB[u] = *(const short8*)(s2 + ((j + 16 * u) << 4));
            }
        } else if (MODE == 2) {
            const char* s1 = (const char*)(Ab1 + ((size_t)row << 8));
            #pragma unroll
            for (int u = 0; u < 2; u++)
                pA[u] = *(const short8*)(s1 + ((j + 16 * u) << 4));
        } else {
            const float* src = Af + (size_t)row * Ktrue;
            #pragma unroll
            for (int v = 0; v < 3; v++) {
                int c = j + 16 * v;                 // 16B f32 chunk, 0..47
                f32x4 val = {0.f, 0.f, 0.f, 0.f};
                if (c * 4 < Ktrue) {
                    if (row == M - 1 && c * 4 + 4 > Ktrue) {
                        #pragma unroll
                        for (int e = 0; e < 4; e++)
                            if (c * 4 + e < Ktrue) val[e] = src[c * 4 + e];
                    } else {
                        val = *(const f32x4u*)(src + c * 4);  // W zero-padded
                    }
                }
                pF[v] = val;
            }
        }
    };
    auto convWrite = [&](int buf) {
        char* dst = (char*)&At[buf][0] + (size_t)r * KP2;
        if (MODE == 1) {
            #pragma unroll
            for (int u = 0; u < 2; u++) {
                short8 a = pA[u], b = pB[u], o;
                #pragma unroll
                for (int e = 0; e < 8; e++)
                    o[e] = f2bs(bs2f(a[e]) - fmaxf(bs2f(b[e]), 0.f));
                int g = j + 16 * u;
                *(short8*)(dst + ((g ^ (r & 7)) << 4)) = o;
            }
        } else if (MODE == 2) {
            #pragma unroll
            for (int u = 0; u < 2; u++) {
                int g = j + 16 * u;
                *(short8*)(dst + ((g ^ (r & 7)) << 4)) = pA[u];
            }
        } else {
            #pragma unroll
            for (int v = 0; v < 3; v++) {
                int c = j + 16 * v;
                f32x4 x = pF[v];
                short4v o;
                #pragma unroll
                for (int e = 0; e < 4; e++) o[e] = f2bs(x[e]);
                int unit = c >> 1, sub = (c & 1) << 3;
                *(short4v*)(dst + ((unit ^ (r & 7)) << 4) + sub) = o;
            }
        }
    };

    prefA(tile);
    int cur = 0;
    for (;;) {
        convWrite(cur);                // waits on this tile's burst (issued
        __syncthreads();               //   one full iteration ago, or prologue)
        const int nxt = tile + GRID;
        const bool more = nxt < ntiles;
        if (more) prefA(nxt);          // next burst into the other reg set era

        f32x4 acc[2][2] = {};
        #pragma unroll
        for (int ks = 0; ks < NK; ks++) {
            short8 afr[2];
            #pragma unroll
            for (int tm = 0; tm < 2; tm++) {
                int ar = tm * 16 + mrow;
                afr[tm] = *(const short8*)((char*)&At[cur][0] + (size_t)ar * KP2 +
                            (((ks * 4 + kq) ^ (ar & 7)) << 4));
            }
            #pragma unroll
            for (int tm = 0; tm < 2; tm++)
                #pragma unroll
                for (int tn = 0; tn < 2; tn++)
                    acc[tm][tn] = __builtin_amdgcn_mfma_f32_16x16x32_bf16(
                        afr[tm], wreg[tn][ks], acc[tm][tn], 0, 0, 0);
        }

        // ---- epilogue: addC direct from global; C/D col=lane&15 row=kq*4+reg
        const int bm = tile * TR;
        #pragma unroll
        for (int tm = 0; tm < 2; tm++) {
            #pragma unroll
            for (int rr = 0; rr < 4; rr++) {
                size_t rb = (size_t)(bm + tm * 16 + kq * 4 + rr) << 8;
                #pragma unroll
                for (int tn = 0; tn < 2; tn++) {
                    int col = wave * 32 + tn * 16 + mrow;
                    float v = acc[tm][tn][rr];
                    if (HASBIAS) v += biasReg[tn];
                    if (ADDC == 1)      v += b2f(addB[rb + col]);
                    else if (ADDC == 2) v += addF[rb + col];
                    if (RELU) v = fmaxf(v, 0.f);
                    if (OUTF32) outF[rb + col] = v;
                    else        outB[rb + col] = f2b(v);
                }
            }
        }
        if (!more) break;
        tile = nxt;
        cur ^= 1;
    }
}

// W[K][256] f32 (rows Koff..Koff+K) -> Wt[256][Kp] bf16, zero pad k in [K,Kp)
__global__ __launch_bounds__(256) void convert_wt(
    const float* __restrict__ W, bf16* __restrict__ Wt, int K, int Koff, int Kp)
{
    int i = blockIdx.x * 256 + threadIdx.x;
    if (i >= 256 * Kp) return;
    int n = i / Kp, k = i - n * Kp;
    Wt[i] = (k < K) ? f2b(W[(size_t)(k + Koff) * 256 + n]) : f2b(0.f);
}

// amsg[a, c8..c8+8) = sum_k relu(msg[a2b[a,k], c8..c8+8)) ; 16B vector loads
__global__ __launch_bounds__(256) void gather_sum8(
    const bf16* __restrict__ msg, const int* __restrict__ a2b,
    bf16* __restrict__ amsg, int A)
{
    int idx = blockIdx.x * 256 + threadIdx.x;
    if (idx >= A * 32) return;
    int a  = idx >> 5;
    int c8 = (idx & 31) * 8;
    const int* nb = a2b + (size_t)a * 6;
    float s[8] = {};
    #pragma unroll
    for (int k = 0; k < 6; k++) {
        const short8 v = *(const short8*)(msg + ((size_t)nb[k] << 8) + c8);
        #pragma unroll
        for (int e = 0; e < 8; e++) s[e] += fmaxf(bs2f(v[e]), 0.f);
    }
    short8 o;
    #pragma unroll
    for (int e = 0; e < 8; e++) o[e] = f2bs(s[e]);
    *(short8*)(amsg + ((size_t)a << 8) + c8) = o;
}

// =============================== MLP (hi/lo) ===============================
#define K3 1536   // 3 * 512

// W[K][N] f32 -> W'[N][K3] bf16 planes [Wh | Wh | Wl], zero-padded k>=K
__global__ __launch_bounds__(256) void conv_w3(
    const float* __restrict__ W, bf16* __restrict__ Wp, int K, int N)
{
    int idx = blockIdx.x * 256 + threadIdx.x;
    if (idx >= N * 512) return;
    int n = idx >> 9, k = idx & 511;
    float w = (k < K) ? W[(size_t)k * N + n] : 0.f;
    bf16 hi = f2b(w);
    bf16 lo = f2b(w - b2f(hi));
    size_t base = (size_t)n * K3;
    Wp[base + k] = hi;
    Wp[base + 512 + k] = hi;
    Wp[base + 1024 + k] = lo;
}

// mol_features -> A1' planes at k in [256,512)  ([Ah | Al | Ah])
__global__ __launch_bounds__(256) void conv_feat(
    const float* __restrict__ mf, bf16* __restrict__ A1p)
{
    int idx = blockIdx.x * 256 + threadIdx.x;   // 4096*256
    int m = idx >> 8, j = idx & 255;
    float v = (j < 200) ? mf[(size_t)m * 200 + j] : 0.f;
    bf16 hi = f2b(v);
    bf16 lo = f2b(v - b2f(hi));
    size_t base = (size_t)m * K3 + 256;
    A1p[base + j] = hi;
    A1p[base + 512 + j] = lo;
    A1p[base + 1024 + j] = hi;
}

// per-molecule mean -> A1' planes at k in [0,256)
__global__ __launch_bounds__(256) void segment_mean3(
    const bf16* __restrict__ ah, const int* __restrict__ atom2mol,
    int A, bf16* __restrict__ A1p)
{
    int m = blockIdx.x;
    int h = threadIdx.x;
    int lo_ = 0, hi_ = A;
    while (lo_ < hi_) { int mid = (lo_ + hi_) >> 1; if (atom2mol[mid] < m) lo_ = mid + 1; else hi_ = mid; }
    int start = lo_;
    hi_ = A;
    while (lo_ < hi_) { int mid = (lo_ + hi_) >> 1; if (atom2mol[mid] <= m) lo_ = mid + 1; else hi_ = mid; }
    int end = lo_;
    float s = 0.f;
    for (int a = start; a < end; a++) s += b2f(ah[(size_t)a * 256 + h]);
    float mean = s / fmaxf((float)(end - start), 1.f);
    bf16 hi = f2b(mean);
    bf16 lo = f2b(mean - b2f(hi));
    size_t base = (size_t)m * K3;
    A1p[base + h] = hi;
    A1p[base + 512 + h] = lo;
    A1p[base + 1024 + h] = hi;
}

// bf16 MFMA GEMM over K3=1536: C = relu(A' @ W'^T + bias).
// 64x64 tile, BK=64, double-buffered LDS, 1 barrier per K-step.
template <bool OUT3>
__global__ __launch_bounds__(256, 2) void gemm3(
    int N,
    const bf16* __restrict__ Ap, const bf16* __restrict__ Wp,
    const float* __restrict__ bias,
    bf16* __restrict__ out3, float* __restrict__ outF)
{
    __shared__ bf16 As[2][64 * 64];
    __shared__ bf16 Bs[2][64 * 64];

    const int t = threadIdx.x;
    const int bm = blockIdx.x * 64, bn = blockIdx.y * 64;
    const int row = t >> 2, q = t & 3;
    const bf16* srcA = Ap + (size_t)(bm + row) * K3 + q * 16;
    const bf16* srcB = Wp + (size_t)(bn + row) * K3 + q * 16;

    short8 ra[2], rb[2];
    auto LOADT = [&](int t0) {
        #pragma unroll
        for (int u = 0; u < 2; u++) {
            ra[u] = *(const short8*)(srcA + t0 * 64 + u * 8);
            rb[u] = *(const short8*)(srcB + t0 * 64 + u * 8);
        }
    };
    auto WRITET = [&](int buf) {
        char* da = (char*)&As[buf][0] + row * 128;
        char* db = (char*)&Bs[buf][0] + row * 128;
        #pragma unroll
        for (int u = 0; u < 2; u++) {
            int g = q * 2 + u;
            *(short8*)(da + ((g ^ (row & 7)) << 4)) = ra[u];
            *(short8*)(db + ((g ^ (row & 7)) << 4)) = rb[u];
        }
    };

    const int wave = t >> 6, lane = t & 63;
    const int mrow = lane & 15, kq = lane >> 4;
    const int wm = (wave >> 1) * 32, wn = (wave & 1) * 32;

    f32x4 acc[2][2] = {};
    LOADT(0);
    WRITET(0);

    for (int t0 = 0; t0 < K3 / 64; t0++) {
        const int cur = t0 & 1;
        __syncthreads();
        if (t0 + 1 < K3 / 64) LOADT(t0 + 1);
        #pragma unroll
        for (int ks = 0; ks < 2; ks++) {
            short8 af[2], bfr[2];
            #pragma unroll
            for (int i = 0; i < 2; i++) {
                int ar = wm + i * 16 + mrow;
                af[i] = *(const short8*)((char*)&As[cur][0] + ar * 128 +
                          (((ks * 4 + kq) ^ (ar & 7)) << 4));
            }
            #pragma unroll
            for (int jx = 0; jx < 2; jx++) {
                int br = wn + jx * 16 + mrow;
                bfr[jx] = *(const short8*)((char*)&Bs[cur][0] + br * 128 +
                          (((ks * 4 + kq) ^ (br & 7)) << 4));
            }
            #pragma unroll
            for (int i = 0; i < 2; i++)
                #pragma unroll
                for (int jx = 0; jx < 2; jx++)
                    acc[i][jx] = __builtin_amdgcn_mfma_f32_16x16x32_bf16(
                        af[i], bfr[jx], acc[i][jx], 0, 0, 0);
        }
        if (t0 + 1 < K3 / 64) WRITET(cur ^ 1);
    }

    #pragma unroll
    for (int i = 0; i < 2; i++) {
        #pragma unroll
        for (int r = 0; r < 4; r++) {
            int grow = bm + wm + i * 16 + kq * 4 + r;
            #pragma unroll
            for (int jx = 0; jx < 2; jx++) {
                int gcol = bn + wn + jx * 16 + mrow;
                float v = acc[i][jx][r] + bias[gcol];
                v = fmaxf(v, 0.f);
                if (OUT3) {
                    bf16 hi = f2b(v);
                    bf16 lo = f2b(v - b2f(hi));
                    size_t base = (size_t)grow * K3;
                    out3[base + gcol] = hi;
                    out3[base + 512 + gcol] = lo;
                    out3[base + 1024 + gcol] = hi;
                } else {
                    outF[(size_t)grow * N + gcol] = v;
                }
            }
        }
    }
}

extern "C" void kernel_launch(void* const* d_in, const int* in_sizes, int n_in,
                              void* d_out, int out_size, void* d_ws, size_t ws_size,
                              hipStream_t stream)
{
    const float* f_atoms  = (const float*)d_in[0];
    const float* f_bonds  = (const float*)d_in[1];
    const int*   a2b      = (const int*)d_in[2];
    const int*   b2a      = (const int*)d_in[3];
    const int*   b2revb   = (const int*)d_in[4];
    const int*   atom2mol = (const int*)d_in[5];
    const float* mol_feat = (const float*)d_in[6];
    const float* W_i      = (const float*)d_in[7];
    const float* W_h      = (const float*)d_in[8];
    const float* W_o_w    = (const float*)d_in[9];
    const float* W_o_b    = (const float*)d_in[10];
    const float* W1       = (const float*)d_in[11];
    const float* b1       = (const float*)d_in[12];
    const float* W2       = (const float*)d_in[13];
    const float* b2       = (const float*)d_in[14];

    const int A  = 100000, B = 200000, H = 256;
    const int AF = 133, BF = 147;
    const int NM = 4096, FH = 512, EH = 256;
    const int KpS = 192;
    const int KpH = 256;

    char* ws = (char*)d_ws;
    bf16* buf0 = (bf16*)ws;  ws += (size_t)B * H * sizeof(bf16);     // 102.4 MB
    bf16* buf1 = (bf16*)ws;  ws += (size_t)B * H * sizeof(bf16);     // 102.4 MB (also f32 fbuf)
    bf16* amsg = (bf16*)ws;  ws += (size_t)A * H * sizeof(bf16);     //  51.2 MB
    bf16* WtI  = (bf16*)ws;  ws += (size_t)256 * KpS * sizeof(bf16);
    bf16* WtH  = (bf16*)ws;  ws += (size_t)256 * KpH * sizeof(bf16);
    bf16* WtO1 = (bf16*)ws;  ws += (size_t)256 * KpS * sizeof(bf16);
    bf16* WtO2 = (bf16*)ws;  ws += (size_t)256 * KpH * sizeof(bf16);
    bf16* W1p  = (bf16*)ws;  ws += (size_t)FH * K3 * sizeof(bf16);   // 1.57 MB
    bf16* W2p  = (bf16*)ws;  ws += (size_t)EH * K3 * sizeof(bf16);   // 0.79 MB
    float* fbuf = (float*)buf1;            // A*256*4 B == B*256*2 B exactly
    bf16* A1p = buf0;                      // overlay: buf0 free after step 3
    bf16* A2p = buf0 + (size_t)NM * K3;

    dim3 blk(256), blkG(512);
    const int ntB = B / TR;                   // 6250
    const int ntA = A / TR;                   // 3125
    const int gsG = (A * 32 + 255) / 256;     // 12500

    // 0. weight conversions
    convert_wt<<<dim3((256 * KpS + 255) / 256), blk, 0, stream>>>(W_i,   WtI,  BF,  0,  KpS);
    convert_wt<<<dim3((256 * KpH + 255) / 256), blk, 0, stream>>>(W_h,   WtH,  H,   0,  KpH);
    convert_wt<<<dim3((256 * KpS + 255) / 256), blk, 0, stream>>>(W_o_w, WtO1, AF,  0,  KpS);
    convert_wt<<<dim3((256 * KpH + 255) / 256), blk, 0, stream>>>(W_o_w, WtO2, H,   AF, KpH);
    conv_w3<<<dim3((FH * 512 + 255) / 256), blk, 0, stream>>>(W1, W1p, H + 200, FH);
    conv_w3<<<dim3((EH * 512 + 255) / 256), blk, 0, stream>>>(W2, W2p, FH, EH);

    // 1. buf0 = f_bonds @ W_i  (pre-relu)
    gemm_wres<192, 0, false, 0, false, false><<<dim3(GRID), blkG, 0, stream>>>(
        B, ntB, BF, f_bonds, nullptr, nullptr, nullptr, nullptr,
        WtI, nullptr, nullptr, nullptr, buf0, nullptr);

    // 2a. iter 1
    gather_sum8<<<dim3(gsG), blk, 0, stream>>>(buf0, a2b, amsg, A);
    gemm_wres<256, 1, true, 1, false, false><<<dim3(GRID), blkG, 0, stream>>>(
        B, ntB, H, nullptr, amsg, buf0, b2a, b2revb,
        WtH, nullptr, buf0, nullptr, buf1, nullptr);

    // 2b. iter 2 (in-place into buf0; addC read-before-write same thread)
    gather_sum8<<<dim3(gsG), blk, 0, stream>>>(buf1, a2b, amsg, A);
    gemm_wres<256, 1, true, 1, false, false><<<dim3(GRID), blkG, 0, stream>>>(
        B, ntB, H, nullptr, amsg, buf1, b2a, b2revb,
        WtH, nullptr, buf0, nullptr, buf0, nullptr);

    // 3. final neighbor sum (last use of buf0 as message buffer)
    gather_sum8<<<dim3(gsG), blk, 0, stream>>>(buf0, a2b, amsg, A);

    // A1' feature part (buf0 region now free)
    conv_feat<<<dim3(NM), blk, 0, stream>>>(mol_feat, A1p);

    // 4a. fbuf = f_atoms @ W_o[0:133]  (f32 partials)
    gemm_wres<192, 0, false, 0, false, true><<<dim3(GRID), blkG, 0, stream>>>(
        A, ntA, AF, f_atoms, nullptr, nullptr, nullptr, nullptr,
        WtO1, nullptr, nullptr, nullptr, nullptr, fbuf);

    // 4b. amsg = relu(fbuf + amsg @ W_o[133:] + b)   (in-place over amsg)
    gemm_wres<256, 2, true, 2, true, false><<<dim3(GRID), blkG, 0, stream>>>(
        A, ntA, H, nullptr, amsg, nullptr, nullptr, nullptr,
        WtO2, W_o_b, nullptr, fbuf, amsg, nullptr);

    // 5. per-molecule mean -> A1' planes
    segment_mean3<<<dim3(NM), blk, 0, stream>>>(amsg, atom2mol, A, A1p);

    // 6. A2' = relu(A1' @ W1' + b1)   (hi/lo planes)
    gemm3<true><<<dim3(NM / 64, FH / 64), blk, 0, stream>>>(
        FH, A1p, W1p, b1, A2p, nullptr);

    // 7. out = relu(A2' @ W2' + b2)
    gemm3<false><<<dim3(NM / 64, EH / 64), blk, 0, stream>>>(
        EH, A2p, W2p, b2, nullptr, (float*)d_out);
}